// Round 7
// baseline (325.398 us; speedup 1.0000x reference)
//
#include <hip/hip_runtime.h>
#include <hip/hip_bf16.h>

using bf16 = __hip_bfloat16;
typedef __attribute__((ext_vector_type(8))) short bf16x8;
typedef __attribute__((ext_vector_type(4))) float f32x4;
typedef __attribute__((ext_vector_type(16))) float f32x16;
typedef __attribute__((ext_vector_type(4))) unsigned int u32x4;

constexpr int Bz  = 2;
constexpr int SEQ = 2048;
constexpr int DM  = 2048;
constexpr int H   = 16;
constexpr int HD  = 128;
constexpr long MROWS = (long)Bz * SEQ;   // 4096
constexpr int EQ  = 3 * DM;              // 6144
// 1/sqrt(128) * log2(e): fold softmax base-2 conversion into Q scaling
constexpr float QSCALE_L2E = 0.12751743427795914f;

__device__ __forceinline__ float bf2f(bf16 x) { return __bfloat162float(x); }
__device__ __forceinline__ bf16  f2bf(float x) { return __float2bfloat16(x); }
__device__ __forceinline__ float rawbf(short u) {
  return __uint_as_float(((unsigned int)(unsigned short)u) << 16);
}

__device__ __forceinline__ float fexp2(float x) {
  float r;
  asm("v_exp_f32 %0, %1" : "=v"(r) : "v"(x));
  return r;
}

template <int N>
__device__ __forceinline__ void waitvm() {
  asm volatile("s_waitcnt vmcnt(%0)" ::"n"(N) : "memory");
}

__device__ __forceinline__ void gl_lds16(const void* g, void* l) {
  __builtin_amdgcn_global_load_lds(
      (const __attribute__((address_space(1))) unsigned int*)g,
      (__attribute__((address_space(3))) unsigned int*)l, 16, 0, 0);
}

// ---------------- fp32 -> bf16 convert (vectorized) ----------------
__global__ void f32_to_bf16(const float* __restrict__ in, bf16* __restrict__ out, long n) {
  long i = ((long)blockIdx.x * blockDim.x + threadIdx.x) * 4;
  if (i >= n) return;
  float4 v = *(const float4*)(in + i);
  bf16 tmp[4] = {f2bf(v.x), f2bf(v.y), f2bf(v.z), f2bf(v.w)};
  *(uint2*)(out + i) = *(uint2*)tmp;
}

// ---------------- RoPE table ----------------
__global__ void rope_table(float* __restrict__ ct, float* __restrict__ st) {
  int idx = blockIdx.x * 256 + threadIdx.x;
  if (idx >= SEQ * 64) return;
  int j = idx & 63, n = idx >> 6;
  double inv = exp(-(double)j / 64.0 * 9.210340371976184); // 10000^{-j/64}
  double a = (double)n * inv;
  ct[idx] = (float)cos(a);
  st[idx] = (float)sin(a);
}

// ============== m201-port 8-phase GEMM: C[M,N] = A[M,K]*B[N,K]^T (+bias) ==============
// BM=128, BN in {384,256}. 8 waves (2M x 4N), per-wave 64 x BN/4.
// 2 K-tiles per iteration (buf0/buf1), 8 phases, 2 barriers/phase.
// Frag-persistent reads: P1: A(i0-1)+B(jh0) [4+2JH], P2: B(jh1) [2JH], P3: A(i2-3) [4], P4: 0.
// Staging in WAR-aligned chunks (1 chunk/phase): CA1/CA2 = A stripes fully read in P1/P3,
// CB1/CB2 = B stripes fully read in P1/P2. vmcnt ONLY at P4/P8, N = 1+2*LB (3 chunks kept
// in flight; every chunk has >=4 phases issue->use). Schedule per iteration (t0,t1):
//   P1:CA2(t1) P2:CA1(t0+2) P3:CB1(t0+2) P4:CB2(t0+2)+vm P5:CA2(t0+2) P6:CA1(t1+2)
//   P7:CB1(t1+2) P8:CB2(t1+2)+vm      (RAW/WAR verified chunk-by-chunk)
template <int KTOT, int BN, int OUT_BF16>
__global__ __launch_bounds__(512) void gemm8p(const bf16* __restrict__ A,
                                              const bf16* __restrict__ Bm,
                                              void* __restrict__ Cv,
                                              const float* __restrict__ bias,
                                              int M, int Nn) {
  constexpr int NT = KTOT / 64;
  constexpr int NITER = NT / 2;
  constexpr int NJ = BN / 64;       // j-frags per wave: 6 or 4
  constexpr int JH = NJ / 2;        // frags per j-half
  constexpr int LB = BN / 128;      // gl_lds per B-chunk: 3 or 2
  constexpr int HB = JH * 16;       // B stripe height: 48 or 32
  constexpr int NWAIT = 1 + 2 * LB; // steady vmcnt: 7 or 5

  __shared__ alignas(16) bf16 lsA[2][128 * 64];
  __shared__ alignas(16) bf16 lsB[2][BN * 64];

  // bijective XCD swizzle (nwg % 8 == 0 for both grids)
  const int nwg = gridDim.x;
  const int f = blockIdx.x;
  const int wg = (f & 7) * (nwg >> 3) + (f >> 3);
  const int nbm = M >> 7;
  const long am0 = (long)(wg % nbm) * 128;
  const long bn0 = (long)(wg / nbm) * BN;

  const int tid = threadIdx.x;
  const int wv = tid >> 6, ln = tid & 63;
  const int wm = wv & 1, wn = wv >> 1;      // 2 x 4 wave grid
  const int fr = ln & 15, kq = ln >> 4;

  f32x4 acc[4][NJ] = {};
  bf16x8 af[4];       // current A i-pair x 2 ks
  bf16x8 bq[NJ][2];   // all B j-frags (persist across the K-tile)

  // ---- chunk staging (dest wave-uniform; source pre-swizzled per lane)
  auto stageA = [&](int buf, int t, int half) {
    const int ric = tid >> 3;
    const int ric0 = wv * 8;
    const int r  = (ric & 31) + ((ric >> 5) << 6) + half * 32;
    const int r0 = (ric0 & 31) + ((ric0 >> 5) << 6) + half * 32;
    const int sl = (tid & 7) ^ (r & 7);
    gl_lds16(A + (am0 + r) * KTOT + t * 64 + sl * 8, &lsA[buf][r0 * 64]);
  };
  auto stageB = [&](int buf, int t, int half) {
#pragma unroll
    for (int ld = 0; ld < LB; ++ld) {
      const int ric = (ld * 512 + tid) >> 3;
      const int ric0 = ld * 64 + wv * 8;
      const int r  = (ric % HB) + (ric / HB) * (2 * HB) + half * HB;
      const int r0 = (ric0 % HB) + (ric0 / HB) * (2 * HB) + half * HB;
      const int sl = (tid & 7) ^ (r & 7);
      gl_lds16(Bm + (bn0 + r) * KTOT + t * 64 + sl * 8, &lsB[buf][r0 * 64]);
    }
  };

  auto rdA = [&](int buf, int ih) {
#pragma unroll
    for (int ip = 0; ip < 2; ++ip)
#pragma unroll
      for (int ks = 0; ks < 2; ++ks) {
        const int row = wm * 64 + (ih * 2 + ip) * 16 + fr;
        const int sl = (ks * 4 + kq) ^ (row & 7);
        af[ip * 2 + ks] = *(const bf16x8*)((const char*)&lsA[buf][0] + row * 128 + sl * 16);
      }
  };
  auto rdB = [&](int buf, int jh) {
#pragma unroll
    for (int jx = 0; jx < JH; ++jx)
#pragma unroll
      for (int ks = 0; ks < 2; ++ks) {
        const int row = wn * (BN / 4) + (jh * JH + jx) * 16 + fr;
        const int sl = (ks * 4 + kq) ^ (row & 7);
        bq[jh * JH + jx][ks] = *(const bf16x8*)((const char*)&lsB[buf][0] + row * 128 + sl * 16);
      }
  };
  auto do_mfma = [&](int ih, int jh) {
    __builtin_amdgcn_s_setprio(1);
#pragma unroll
    for (int ip = 0; ip < 2; ++ip)
#pragma unroll
      for (int jx = 0; jx < JH; ++jx)
#pragma unroll
        for (int ks = 0; ks < 2; ++ks)
          acc[ih * 2 + ip][jh * JH + jx] = __builtin_amdgcn_mfma_f32_16x16x32_bf16(
              af[ip * 2 + ks], bq[jh * JH + jx][ks], acc[ih * 2 + ip][jh * JH + jx], 0, 0, 0);
    __builtin_amdgcn_s_setprio(0);
  };
  auto bar = [&]() { __builtin_amdgcn_s_barrier(); };

  // ---- prologue: tile0 fully + tile1 CA1,CB1,CB2 (CA2(1) staged in-loop at P1)
  stageA(0, 0, 0); stageB(0, 0, 0); stageB(0, 0, 1); stageA(0, 0, 1);
  stageA(1, 1, 0); stageB(1, 1, 0); stageB(1, 1, 1);
  waitvm<NWAIT>();   // leaves tile1's 1+2LB -> tile0 complete
  bar();

  for (int it = 0; it < NITER; ++it) {
    const int t0 = 2 * it;
    const bool pre = (it + 1 < NITER);
    // ---- P1 (buf0, quad 0,0)
    rdA(0, 0); rdB(0, 0);
    stageA(1, t0 + 1, 1);                 // CA2(t1)
    bar(); do_mfma(0, 0); bar();
    // ---- P2 (0,1)
    rdB(0, 1);
    if (pre) stageA(0, t0 + 2, 0);        // CA1(t0+2)
    bar(); do_mfma(0, 1); bar();
    // ---- P3 (1,0)
    rdA(0, 1);
    if (pre) stageB(0, t0 + 2, 0);        // CB1(t0+2)
    bar(); do_mfma(1, 0); bar();
    // ---- P4 (1,1) + vmcnt
    if (pre) { stageB(0, t0 + 2, 1); waitvm<NWAIT>(); }
    else     { waitvm<0>(); }
    bar(); do_mfma(1, 1); bar();
    // ---- P5 (buf1, quad 0,0)
    rdA(1, 0); rdB(1, 0);
    if (pre) stageA(0, t0 + 2, 1);        // CA2(t0+2)
    bar(); do_mfma(0, 0); bar();
    // ---- P6 (0,1)
    rdB(1, 1);
    if (pre) stageA(1, t0 + 3, 0);        // CA1(t1+2)
    bar(); do_mfma(0, 1); bar();
    // ---- P7 (1,0)
    rdA(1, 1);
    if (pre) stageB(1, t0 + 3, 0);        // CB1(t1+2)
    bar(); do_mfma(1, 0); bar();
    // ---- P8 (1,1) + vmcnt
    if (pre) { stageB(1, t0 + 3, 1); waitvm<NWAIT>(); }
    bar(); do_mfma(1, 1); bar();
  }

  // epilogue (registers only; no LDS reuse)
#pragma unroll
  for (int i = 0; i < 4; ++i) {
    const long row0 = am0 + wm * 64 + i * 16 + kq * 4;
#pragma unroll
    for (int j = 0; j < NJ; ++j) {
      const long col = bn0 + wn * (BN / 4) + j * 16 + fr;
      const float bv = bias ? bias[col] : 0.f;
#pragma unroll
      for (int q = 0; q < 4; ++q) {
        const float v = acc[i][j][q] + bv;
        if (OUT_BF16) ((bf16*)Cv)[(row0 + q) * Nn + col] = f2bf(v);
        else          ((float*)Cv)[(row0 + q) * Nn + col] = v;
      }
    }
  }
}

// ---------------- RoPE + head reshape (bf16x8 vectorized) ----------------
__global__ void rope_reshape(const bf16* __restrict__ qkv, const float* __restrict__ ct,
                             const float* __restrict__ st, bf16* __restrict__ q_r,
                             bf16* __restrict__ k_r) {
  long idx = (long)blockIdx.x * 256 + threadIdx.x;
  int j8 = (idx & 7) * 8;
  int h = (idx >> 3) & 15;
  int n = (idx >> 7) & 2047;
  int b = (int)(idx >> 18);
  long row = (long)b * SEQ + n;
  long qoff = row * EQ + h * 128 + j8;
  bf16x8 q1v = *(const bf16x8*)(qkv + qoff);
  bf16x8 q2v = *(const bf16x8*)(qkv + qoff + 64);
  bf16x8 k1v = *(const bf16x8*)(qkv + qoff + 2048);
  bf16x8 k2v = *(const bf16x8*)(qkv + qoff + 2048 + 64);
  float4 ca = *(const float4*)(ct + n * 64 + j8);
  float4 cb = *(const float4*)(ct + n * 64 + j8 + 4);
  float4 sa = *(const float4*)(st + n * 64 + j8);
  float4 sb = *(const float4*)(st + n * 64 + j8 + 4);
  float c[8] = {ca.x, ca.y, ca.z, ca.w, cb.x, cb.y, cb.z, cb.w};
  float s[8] = {sa.x, sa.y, sa.z, sa.w, sb.x, sb.y, sb.z, sb.w};
  bf16x8 oq1, oq2, ok1, ok2;
#pragma unroll
  for (int m = 0; m < 8; ++m) {
    float q1 = rawbf(q1v[m]), q2 = rawbf(q2v[m]);
    float k1 = rawbf(k1v[m]), k2 = rawbf(k2v[m]);
    oq1[m] = (short)__bfloat16_as_ushort(f2bf((q1 * c[m] - q2 * s[m]) * QSCALE_L2E));
    oq2[m] = (short)__bfloat16_as_ushort(f2bf((q1 * s[m] + q2 * c[m]) * QSCALE_L2E));
    ok1[m] = (short)__bfloat16_as_ushort(f2bf(k1 * c[m] - k2 * s[m]));
    ok2[m] = (short)__bfloat16_as_ushort(f2bf(k1 * s[m] + k2 * c[m]));
  }
  long obase = ((long)(b * 16 + h) * SEQ + n) * HD + j8;
  *(bf16x8*)(q_r + obase)      = oq1;
  *(bf16x8*)(q_r + obase + 64) = oq2;
  *(bf16x8*)(k_r + obase)      = ok1;
  *(bf16x8*)(k_r + obase + 64) = ok2;
}

// ---------------- V transpose (vectorized both global sides) ----------------
__global__ __launch_bounds__(256) void v_transpose(const bf16* __restrict__ qkv,
                                                   bf16* __restrict__ v_t) {
  __shared__ bf16 tile[64][72];
  int bh = blockIdx.z;
  int b = bh >> 4, h = bh & 15;
  int n0 = blockIdx.y * 64, d0 = blockIdx.x * 64;
  int t = threadIdx.x;
#pragma unroll
  for (int it = 0; it < 2; ++it) {
    int e = it * 256 + t;
    int nn = e >> 3, dn8 = (e & 7) * 8;
    bf16x8 v = *(const bf16x8*)(qkv + (long)(b * SEQ + n0 + nn) * EQ + 2 * DM + h * 128 + d0 + dn8);
#pragma unroll
    for (int m = 0; m < 8; ++m) tile[nn][dn8 + m] = __ushort_as_bfloat16((unsigned short)v[m]);
  }
  __syncthreads();
#pragma unroll
  for (int it = 0; it < 2; ++it) {
    int e = it * 256 + t;
    int dd = e >> 3, nn8 = (e & 7) * 8;
    bf16x8 o;
#pragma unroll
    for (int m = 0; m < 8; ++m)
      o[m] = (short)__bfloat16_as_ushort(tile[nn8 + m][dd]);
    *(bf16x8*)(v_t + ((long)bh * HD + d0 + dd) * SEQ + n0 + nn8) = o;
  }
}

// ---------------- Flash attention: 8 waves, swapped-QK^T 32x32, defer-max ----------------
__global__ __launch_bounds__(512, 2) void attn_fwd(const bf16* __restrict__ q_r,
                                                   const bf16* __restrict__ k_r,
                                                   const bf16* __restrict__ v_t,
                                                   bf16* __restrict__ ao) {
  __shared__ alignas(16) char lds[69632];

  // XCD grouping: 256 blocks; XCD x hosts bh in [4x, 4x+4) (4MB KV = one L2)
  const int flat = blockIdx.x;                       // 0..255
  const int bh = (flat & 7) * 4 + (flat >> 6);
  const int qt = (flat >> 3) & 7;
  const int b = bh >> 4, h = bh & 15;

  const int wv = threadIdx.x >> 6, ln = threadIdx.x & 63;
  const int lh = ln >> 5;
  const int lq = ln & 31;
  const int q0 = qt * 256 + wv * 32;

  bf16x8 aq[8];
  {
    const char* qbase = (const char*)(q_r + ((long)bh * SEQ + q0 + lq) * HD);
#pragma unroll
    for (int ks = 0; ks < 8; ++ks)
      aq[ks] = *(const bf16x8*)(qbase + ks * 32 + lh * 16);
  }

  f32x16 oacc[4] = {};
  float mrow = -1e30f, lsum = 0.f;

  auto stage = [&](int buf, int t) {
    char* kb = lds + buf * 16384;
    char* vb = lds + 32768 + buf * 16384;
#pragma unroll
    for (int cc = 0; cc < 4; ++cc) {
      const int chunk = wv * 4 + cc;          // 0..15 K, 16..31 V
      if (chunk < 16) {
        const int r = chunk * 4 + (ln >> 4);
        const char* src = (const char*)k_r + ((long)bh * SEQ + t * 64 + r) * 256 +
                          (((ln & 15) ^ (r & 15)) << 4);
        gl_lds16(src, kb + chunk * 1024);
      } else {
        const int c2 = chunk - 16;
        const int r = c2 * 8 + (ln >> 3);
        const char* src = (const char*)v_t + ((long)bh * HD + r) * (SEQ * 2) + t * 128 +
                          (((ln & 7) ^ (r & 7)) << 4);
        gl_lds16(src, vb + c2 * 1024);
      }
    }
  };

  stage(0, 0);
  __syncthreads();

  for (int t = 0; t < SEQ / 64; ++t) {
    const int cur = t & 1;
    if (t + 1 < SEQ / 64) stage(cur ^ 1, t + 1);
    const char* kb = lds + cur * 16384;
    const char* vb = lds + 32768 + cur * 16384;

    f32x16 sacc[2] = {};
    __builtin_amdgcn_s_setprio(1);
#pragma unroll
    for (int kvs = 0; kvs < 2; ++kvs) {
      const int kv = kvs * 32 + lq;
#pragma unroll
      for (int ks = 0; ks < 8; ++ks) {
        bf16x8 kf = *(const bf16x8*)(kb + kv * 256 + ((((ks << 1) | lh) ^ (kv & 15)) << 4));
        sacc[kvs] = __builtin_amdgcn_mfma_f32_32x32x16_bf16(kf, aq[ks], sacc[kvs], 0, 0, 0);
      }
    }
    __builtin_amdgcn_s_setprio(0);

    float mx = sacc[0][0];
#pragma unroll
    for (int r = 1; r < 16; ++r) mx = fmaxf(mx, sacc[0][r]);
#pragma unroll
    for (int r = 0; r < 16; ++r) mx = fmaxf(mx, sacc[1][r]);
    mx = fmaxf(mx, __shfl_xor(mx, 32, 64));

    // defer-max (T13)
    if (!__all(mx - mrow <= 8.0f)) {
      const float mn = fmaxf(mrow, mx);
      const float scale = fexp2(mrow - mn);
      mrow = mn;
      lsum *= scale;
#pragma unroll
      for (int dt = 0; dt < 4; ++dt) oacc[dt] *= scale;
    }
    float psum = 0.f;
#pragma unroll
    for (int k2 = 0; k2 < 2; ++k2)
#pragma unroll
      for (int r = 0; r < 16; ++r) {
        const float pv = fexp2(sacc[k2][r] - mrow);
        sacc[k2][r] = pv;
        psum += pv;
      }
    psum += __shfl_xor(psum, 32, 64);
    lsum += psum;

    bf16x8 pfrag[4];
#pragma unroll
    for (int k2 = 0; k2 < 2; ++k2) {
      unsigned int pk[8];
#pragma unroll
      for (int i = 0; i < 8; ++i) {
        unsigned int lo = __bfloat16_as_ushort(f2bf(sacc[k2][2 * i]));
        unsigned int hi = __bfloat16_as_ushort(f2bf(sacc[k2][2 * i + 1]));
        pk[i] = lo | (hi << 16);
      }
#pragma unroll
      for (int fb = 0; fb < 2; ++fb) {
        const unsigned int a0 = pk[fb * 4 + 0], a1 = pk[fb * 4 + 1];
        const unsigned int b0 = pk[fb * 4 + 2], b1 = pk[fb * 4 + 3];
        const unsigned int sb0 = __shfl_xor(b0, 32, 64);
        const unsigned int sb1 = __shfl_xor(b1, 32, 64);
        const unsigned int sa0 = __shfl_xor(a0, 32, 64);
        const unsigned int sa1 = __shfl_xor(a1, 32, 64);
        u32x4 wvec;
        wvec.x = lh ? sb0 : a0;
        wvec.y = lh ? sb1 : a1;
        wvec.z = lh ? b0 : sa0;
        wvec.w = lh ? b1 : sa1;
        pfrag[k2 * 2 + fb] = __builtin_bit_cast(bf16x8, wvec);
      }
    }

    __builtin_amdgcn_s_setprio(1);
#pragma unroll
    for (int dt = 0; dt < 4; ++dt) {
      const int d = dt * 32 + lq;
#pragma unroll
      for (int kk = 0; kk < 4; ++kk) {
        bf16x8 vf = *(const bf16x8*)(vb + d * 128 + ((((kk << 1) | lh) ^ (d & 7)) << 4));
        oacc[dt] = __builtin_amdgcn_mfma_f32_32x32x16_bf16(vf, pfrag[kk], oacc[dt], 0, 0, 0);
      }
    }
    __builtin_amdgcn_s_setprio(0);
    __syncthreads();
  }

  // epilogue: O^T -> LDS transpose -> coalesced store
  const float inv = 1.0f / lsum;
  bf16* ob = (bf16*)lds;
  const int qloc = wv * 32 + lq;
#pragma unroll
  for (int dt = 0; dt < 4; ++dt)
#pragma unroll
    for (int r = 0; r < 16; ++r) {
      const int d = dt * 32 + (r & 3) + 8 * (r >> 2) + 4 * lh;
      ob[qloc * 132 + d] = f2bf(oacc[dt][r] * inv);
    }
#pragma unroll
  for (int it = 0; it < 8; ++it) {
    const int c = it * 64 + ln;
    const int qq = c >> 4, dc = c & 15;
    const char* srcp = (const char*)ob + (wv * 32 + qq) * 264 + dc * 16;
    uint2 v0 = *(const uint2*)srcp;
    uint2 v1 = *(const uint2*)(srcp + 8);
    uint4 outv;
    outv.x = v0.x; outv.y = v0.y; outv.z = v1.x; outv.w = v1.y;
    *(uint4*)((char*)(ao + ((long)b * SEQ + qt * 256 + wv * 32 + qq) * DM + h * 128) + dc * 16) = outv;
  }
}

// ---------------- launch ----------------
extern "C" void kernel_launch(void* const* d_in, const int* in_sizes, int n_in,
                              void* d_out, int out_size, void* d_ws, size_t ws_size,
                              hipStream_t stream) {
  const float* x      = (const float*)d_in[0];
  const float* w_qkv  = (const float*)d_in[1];
  const float* w_proj = (const float*)d_in[2];
  const float* b_proj = (const float*)d_in[3];

  char* ws = (char*)d_ws;
  size_t off = 0;
  auto alloc = [&](size_t bytes) {
    void* p = ws + off;
    off += (bytes + 255) & ~(size_t)255;
    return p;
  };
  bf16* xb     = (bf16*)alloc((size_t)MROWS * DM * 2);
  bf16* wqkvb  = (bf16*)alloc((size_t)EQ * DM * 2);
  bf16* wprojb = (bf16*)alloc((size_t)DM * DM * 2);
  bf16* qkvb   = (bf16*)alloc((size_t)MROWS * EQ * 2);
  bf16* q_r    = (bf16*)alloc((size_t)Bz * H * SEQ * HD * 2);
  bf16* k_r    = (bf16*)alloc((size_t)Bz * H * SEQ * HD * 2);
  bf16* v_t    = (bf16*)alloc((size_t)Bz * H * SEQ * HD * 2);
  bf16* aob    = (bf16*)alloc((size_t)MROWS * DM * 2);
  float* ct    = (float*)alloc((size_t)SEQ * 64 * 4);
  float* st    = (float*)alloc((size_t)SEQ * 64 * 4);

  {
    long n = MROWS * DM;
    f32_to_bf16<<<(int)((n / 4 + 255) / 256), 256, 0, stream>>>(x, xb, n);
  }
  {
    long n = (long)EQ * DM;
    f32_to_bf16<<<(int)((n / 4 + 255) / 256), 256, 0, stream>>>(w_qkv, wqkvb, n);
  }
  {
    long n = (long)DM * DM;
    f32_to_bf16<<<(int)((n / 4 + 255) / 256), 256, 0, stream>>>(w_proj, wprojb, n);
  }
  rope_table<<<(SEQ * 64) / 256, 256, 0, stream>>>(ct, st);

  // GEMM1: 4096x6144x2048, BM=128 BN=384 -> grid 512 = 2 exact rounds
  gemm8p<2048, 384, 1><<<(int)(MROWS / 128) * (EQ / 384), 512, 0, stream>>>(
      xb, wqkvb, qkvb, nullptr, (int)MROWS, EQ);

  rope_reshape<<<(int)((long)Bz * SEQ * H * 8 / 256), 256, 0, stream>>>(qkvb, ct, st, q_r, k_r);
  v_transpose<<<dim3(HD / 64, SEQ / 64, Bz * H), 256, 0, stream>>>(qkvb, v_t);

  // attn: 256 blocks (1 exact round), 8 waves each
  attn_fwd<<<256, 512, 0, stream>>>(q_r, k_r, v_t, aob);

  // GEMM2: 4096x2048x2048, BM=128 BN=256 -> grid 256 = 1 exact round
  gemm8p<2048, 256, 0><<<(int)(MROWS / 128) * (DM / 256), 512, 0, stream>>>(
      aob, wprojb, d_out, b_proj, (int)MROWS, DM);
}

// Round 9
// 238.392 us; speedup vs baseline: 1.3650x; 1.3650x over previous
//
#include <hip/hip_runtime.h>
#include <hip/hip_bf16.h>

using bf16 = __hip_bfloat16;
typedef __attribute__((ext_vector_type(8))) short bf16x8;
typedef __attribute__((ext_vector_type(4))) float f32x4;
typedef __attribute__((ext_vector_type(16))) float f32x16;
typedef __attribute__((ext_vector_type(4))) unsigned int u32x4;

constexpr int Bz  = 2;
constexpr int SEQ = 2048;
constexpr int DM  = 2048;
constexpr int H   = 16;
constexpr int HD  = 128;
constexpr long MROWS = (long)Bz * SEQ;   // 4096
constexpr int EQ  = 3 * DM;              // 6144
// 1/sqrt(128) * log2(e): fold softmax base-2 conversion into Q scaling
constexpr float QSCALE_L2E = 0.12751743427795914f;

__device__ __forceinline__ float bf2f(bf16 x) { return __bfloat162float(x); }
__device__ __forceinline__ bf16  f2bf(float x) { return __float2bfloat16(x); }

__device__ __forceinline__ float fexp2(float x) {
  float r;
  asm("v_exp_f32 %0, %1" : "=v"(r) : "v"(x));
  return r;
}

template <int N>
__device__ __forceinline__ void waitvm() {
  asm volatile("s_waitcnt vmcnt(%0)" ::"n"(N) : "memory");
}

__device__ __forceinline__ void gl_lds16(const void* g, void* l) {
  __builtin_amdgcn_global_load_lds(
      (const __attribute__((address_space(1))) unsigned int*)g,
      (__attribute__((address_space(3))) unsigned int*)l, 16, 0, 0);
}

// ---------------- fp32 -> bf16 convert (vectorized) ----------------
__global__ void f32_to_bf16(const float* __restrict__ in, bf16* __restrict__ out, long n) {
  long i = ((long)blockIdx.x * blockDim.x + threadIdx.x) * 4;
  if (i >= n) return;
  float4 v = *(const float4*)(in + i);
  bf16 tmp[4] = {f2bf(v.x), f2bf(v.y), f2bf(v.z), f2bf(v.w)};
  *(uint2*)(out + i) = *(uint2*)tmp;
}

// ---------------- RoPE table ----------------
__global__ void rope_table(float* __restrict__ ct, float* __restrict__ st) {
  int idx = blockIdx.x * 256 + threadIdx.x;
  if (idx >= SEQ * 64) return;
  int j = idx & 63, n = idx >> 6;
  double inv = exp(-(double)j / 64.0 * 9.210340371976184); // 10000^{-j/64}
  double a = (double)n * inv;
  ct[idx] = (float)cos(a);
  st[idx] = (float)sin(a);
}

// ============== BM=128 x BN GEMM (R5-verified loop), optional fused QKV epilogue ==============
// 8 waves (2M x 4N), per-wave 64 x (BN/4); NBP = BN/128 phases per K-tile(64).
// Phase bp: {reads, stage 1 chunk of t+1, counted vmcnt, barrier, 16 MFMA (setprio)}.
// FUSE=1 (GEMM1): epilogue writes acc col-major to LDS, then applies RoPE (Q/K) and
// V-transpose directly -> q_r/k_r/v_t. Tile cols = 3 full 128-col head segments.
// acc[i][j] <-> local row (wm+2i)*16 + kq*4 + q, local col (wn+4j)*16 + fr   (VERIFIED vs K-loop)
template <int KTOT, int BN, int NBP, int FUSE>
__global__ __launch_bounds__(512) void gemm128(const bf16* __restrict__ A,
                                               const bf16* __restrict__ Bm,
                                               void* __restrict__ Cv,
                                               const float* __restrict__ bias,
                                               bf16* __restrict__ q_r,
                                               bf16* __restrict__ k_r,
                                               bf16* __restrict__ v_t,
                                               const float* __restrict__ ct,
                                               const float* __restrict__ st,
                                               int M, int Nn) {
  constexpr int NT = KTOT / 64;
  constexpr int ASZ = 128 * 64;            // elems per A buf
  constexpr int BSZ = BN * 64;             // elems per B buf
  __shared__ alignas(16) char smem[2 * ASZ * 2 + 2 * BSZ * 2];
  bf16* lsA = (bf16*)smem;                       // [2][ASZ]
  bf16* lsB = (bf16*)(smem + 2 * ASZ * 2);       // [2][BSZ]

  // bijective XCD swizzle (nwg % 8 == 0 for both grids)
  const int nwg = gridDim.x;
  const int f = blockIdx.x;
  const int wg = (f & 7) * (nwg >> 3) + (f >> 3);
  const int nbm = M >> 7;
  const long am0 = (long)(wg % nbm) * 128;
  const long bn0 = (long)(wg / nbm) * BN;

  const int tid = threadIdx.x;
  const int wv = tid >> 6, ln = tid & 63;
  const int wm = wv & 1, wn = wv >> 1;      // 2 x 4 wave grid
  const int fr = ln & 15, kq = ln >> 4;
  const int sr8 = ln >> 3;                  // staging row within 8-row slab
  const int ss  = ln & 7;                   // staging physical 16B slot

  f32x4 acc[4][2 * NBP] = {};

  auto stageA = [&](int buf, int t) {
#pragma unroll
    for (int ld = 0; ld < 2; ++ld) {
      const int r = ld * 64 + wv * 8 + sr8;
      const int sl = ss ^ (r & 7);
      gl_lds16(A + (am0 + r) * KTOT + t * 64 + sl * 8, lsA + buf * ASZ + (ld * 64 + wv * 8) * 64);
    }
  };
  auto stageB = [&](int buf, int t, int bp) {
#pragma unroll
    for (int ld = 0; ld < 2; ++ld) {
      const int r = bp * 128 + ld * 64 + wv * 8 + sr8;
      const int sl = ss ^ (r & 7);
      gl_lds16(Bm + (bn0 + r) * KTOT + t * 64 + sl * 8,
               lsB + buf * BSZ + (bp * 128 + ld * 64 + wv * 8) * 64);
    }
  };

  // prologue: all chunks of tile 0, full drain
  stageA(0, 0);
#pragma unroll
  for (int bp = 0; bp < NBP; ++bp) stageB(0, 0, bp);
  waitvm<0>();
  __builtin_amdgcn_s_barrier();

#pragma unroll 2
  for (int t = 0; t < NT; ++t) {
    const int cur = t & 1;
    const bool pre = (t + 1 < NT);

    bf16x8 af[8];
#pragma unroll
    for (int bp = 0; bp < NBP; ++bp) {
      if (bp == 0) {
#pragma unroll
        for (int i = 0; i < 4; ++i)
#pragma unroll
          for (int ks = 0; ks < 2; ++ks) {
            const int row = (wm + 2 * i) * 16 + fr;
            const int sl = (ks * 4 + kq) ^ (row & 7);
            af[i * 2 + ks] =
                *(const bf16x8*)((const char*)(lsA + cur * ASZ) + row * 128 + sl * 16);
          }
      }
      bf16x8 bq[4];
#pragma unroll
      for (int jj = 0; jj < 2; ++jj)
#pragma unroll
        for (int ks = 0; ks < 2; ++ks) {
          const int row = (wn + 4 * (2 * bp + jj)) * 16 + fr;
          const int sl = (ks * 4 + kq) ^ (row & 7);
          bq[jj * 2 + ks] =
              *(const bf16x8*)((const char*)(lsB + cur * BSZ) + row * 128 + sl * 16);
        }

      if (pre) {
        if (bp == 0) {
          stageA(cur ^ 1, t + 1);
          stageB(cur ^ 1, t + 1, 0);
          waitvm<2 * NBP>();
        } else if (bp == NBP - 1) {
          stageB(cur ^ 1, t + 1, bp);
          waitvm<2 * (NBP - 1)>();
        } else {
          stageB(cur ^ 1, t + 1, bp);
          waitvm<2 * NBP>();
        }
      } else {
        if (bp == 0) waitvm<(NBP > 2) ? 2 : 0>();
        else waitvm<0>();
      }
      __builtin_amdgcn_s_barrier();

      __builtin_amdgcn_s_setprio(1);
#pragma unroll
      for (int i = 0; i < 4; ++i)
#pragma unroll
        for (int jj = 0; jj < 2; ++jj)
#pragma unroll
          for (int ks = 0; ks < 2; ++ks)
            acc[i][2 * bp + jj] = __builtin_amdgcn_mfma_f32_16x16x32_bf16(
                af[i * 2 + ks], bq[jj * 2 + ks], acc[i][2 * bp + jj], 0, 0, 0);
      __builtin_amdgcn_s_setprio(0);
    }
  }

  if constexpr (FUSE) {
    // ---- fused epilogue: acc -> LDS col-major [384 cols][136 rows], then RoPE / V-transpose
    static_assert(BN == 384, "fused epilogue assumes 3 head segments per tile");
    bf16* eb = (bf16*)smem;   // 384*136*2 = 104448 B <= 131072
    __syncthreads();          // drain all waves' K-loop ds_reads before overwriting LDS
#pragma unroll
    for (int i = 0; i < 4; ++i) {
      const int r0 = (wm + 2 * i) * 16 + kq * 4;          // local row (matches K-loop mapping)
#pragma unroll
      for (int j = 0; j < 2 * NBP; ++j) {
        const int c = (wn + 4 * j) * 16 + fr;             // local col (matches K-loop mapping)
        bf16 t4[4];
#pragma unroll
        for (int q = 0; q < 4; ++q) t4[q] = f2bf(acc[i][j][q]);
        *(uint2*)(eb + c * 136 + r0) = *(uint2*)t4;
      }
    }
    __syncthreads();
    const int bb = (int)(am0 >> 11);          // batch (tile rows stay within one b)
    const int nbase = (int)(am0 & 2047);
#pragma unroll
    for (int cb = 0; cb < 3; ++cb) {
      const int gc = (int)bn0 + cb * 128;
      const int seg = gc >> 11;               // 0=Q 1=K 2=V
      const long bh = bb * 16 + ((gc & 2047) >> 7);
      if (seg < 2) {
        bf16* dst = (seg == 0) ? q_r : k_r;
        const float qs = (seg == 0) ? QSCALE_L2E : 1.0f;
        for (int itx = 0; itx < 16; ++itx) {
          const int idx = itx * 512 + tid;
          const int r = idx >> 6, j = idx & 63;
          const int n = nbase + r;
          const float v1 = bf2f(eb[(cb * 128 + j) * 136 + r]);
          const float v2 = bf2f(eb[(cb * 128 + j + 64) * 136 + r]);
          const float cc = ct[n * 64 + j], sv = st[n * 64 + j];
          const long ob = (bh * SEQ + n) * HD + j;
          dst[ob]      = f2bf((v1 * cc - v2 * sv) * qs);
          dst[ob + 64] = f2bf((v1 * sv + v2 * cc) * qs);
        }
      } else {
        for (int itx = 0; itx < 4; ++itx) {
          const int idx = itx * 512 + tid;
          const int d = idx >> 4, n8 = (idx & 15) * 8;
          bf16x8 v = *(const bf16x8*)(eb + (cb * 128 + d) * 136 + n8);
          *(bf16x8*)(v_t + (bh * HD + d) * SEQ + nbase + n8) = v;
        }
      }
    }
  } else {
    // ---- plain epilogue: f32 + bias
#pragma unroll
    for (int i = 0; i < 4; ++i) {
      const long row0 = am0 + (wm + 2 * i) * 16 + kq * 4;
#pragma unroll
      for (int j = 0; j < 2 * NBP; ++j) {
        const long col = bn0 + (wn + 4 * j) * 16 + fr;
        const float bv = bias ? bias[col] : 0.f;
#pragma unroll
        for (int q = 0; q < 4; ++q) {
          const float v = acc[i][j][q] + bv;
          ((float*)Cv)[(row0 + q) * Nn + col] = v;
        }
      }
    }
  }
}

// ---------------- Flash attention: 8 waves, swapped-QK^T 32x32, defer-max ----------------
__global__ __launch_bounds__(512, 2) void attn_fwd(const bf16* __restrict__ q_r,
                                                   const bf16* __restrict__ k_r,
                                                   const bf16* __restrict__ v_t,
                                                   bf16* __restrict__ ao) {
  __shared__ alignas(16) char lds[69632];

  // XCD grouping: 256 blocks; XCD x hosts bh in [4x, 4x+4) (4MB KV = one L2)
  const int flat = blockIdx.x;                       // 0..255
  const int bh = (flat & 7) * 4 + (flat >> 6);
  const int qt = (flat >> 3) & 7;
  const int b = bh >> 4, h = bh & 15;

  const int wv = threadIdx.x >> 6, ln = threadIdx.x & 63;
  const int lh = ln >> 5;
  const int lq = ln & 31;
  const int q0 = qt * 256 + wv * 32;

  bf16x8 aq[8];
  {
    const char* qbase = (const char*)(q_r + ((long)bh * SEQ + q0 + lq) * HD);
#pragma unroll
    for (int ks = 0; ks < 8; ++ks)
      aq[ks] = *(const bf16x8*)(qbase + ks * 32 + lh * 16);
  }

  f32x16 oacc[4] = {};
  float mrow = -1e30f, lsum = 0.f;

  auto stage = [&](int buf, int t) {
    char* kb = lds + buf * 16384;
    char* vb = lds + 32768 + buf * 16384;
#pragma unroll
    for (int cc = 0; cc < 4; ++cc) {
      const int chunk = wv * 4 + cc;          // 0..15 K, 16..31 V
      if (chunk < 16) {
        const int r = chunk * 4 + (ln >> 4);
        const char* src = (const char*)k_r + ((long)bh * SEQ + t * 64 + r) * 256 +
                          (((ln & 15) ^ (r & 15)) << 4);
        gl_lds16(src, kb + chunk * 1024);
      } else {
        const int c2 = chunk - 16;
        const int r = c2 * 8 + (ln >> 3);
        const char* src = (const char*)v_t + ((long)bh * HD + r) * (SEQ * 2) + t * 128 +
                          (((ln & 7) ^ (r & 7)) << 4);
        gl_lds16(src, vb + c2 * 1024);
      }
    }
  };

  stage(0, 0);
  __syncthreads();

  for (int t = 0; t < SEQ / 64; ++t) {
    const int cur = t & 1;
    if (t + 1 < SEQ / 64) stage(cur ^ 1, t + 1);
    const char* kb = lds + cur * 16384;
    const char* vb = lds + 32768 + cur * 16384;

    f32x16 sacc[2] = {};
    __builtin_amdgcn_s_setprio(1);
#pragma unroll
    for (int kvs = 0; kvs < 2; ++kvs) {
      const int kv = kvs * 32 + lq;
#pragma unroll
      for (int ks = 0; ks < 8; ++ks) {
        bf16x8 kf = *(const bf16x8*)(kb + kv * 256 + ((((ks << 1) | lh) ^ (kv & 15)) << 4));
        sacc[kvs] = __builtin_amdgcn_mfma_f32_32x32x16_bf16(kf, aq[ks], sacc[kvs], 0, 0, 0);
      }
    }
    __builtin_amdgcn_s_setprio(0);

    float mx = sacc[0][0];
#pragma unroll
    for (int r = 1; r < 16; ++r) mx = fmaxf(mx, sacc[0][r]);
#pragma unroll
    for (int r = 0; r < 16; ++r) mx = fmaxf(mx, sacc[1][r]);
    mx = fmaxf(mx, __shfl_xor(mx, 32, 64));

    // defer-max (T13)
    if (!__all(mx - mrow <= 8.0f)) {
      const float mn = fmaxf(mrow, mx);
      const float scale = fexp2(mrow - mn);
      mrow = mn;
      lsum *= scale;
#pragma unroll
      for (int dt = 0; dt < 4; ++dt) oacc[dt] *= scale;
    }
    float psum = 0.f;
#pragma unroll
    for (int k2 = 0; k2 < 2; ++k2)
#pragma unroll
      for (int r = 0; r < 16; ++r) {
        const float pv = fexp2(sacc[k2][r] - mrow);
        sacc[k2][r] = pv;
        psum += pv;
      }
    psum += __shfl_xor(psum, 32, 64);
    lsum += psum;

    bf16x8 pfrag[4];
#pragma unroll
    for (int k2 = 0; k2 < 2; ++k2) {
      unsigned int pk[8];
#pragma unroll
      for (int i = 0; i < 8; ++i) {
        unsigned int lo = __bfloat16_as_ushort(f2bf(sacc[k2][2 * i]));
        unsigned int hi = __bfloat16_as_ushort(f2bf(sacc[k2][2 * i + 1]));
        pk[i] = lo | (hi << 16);
      }
#pragma unroll
      for (int fb = 0; fb < 2; ++fb) {
        const unsigned int a0 = pk[fb * 4 + 0], a1 = pk[fb * 4 + 1];
        const unsigned int b0 = pk[fb * 4 + 2], b1 = pk[fb * 4 + 3];
        const unsigned int sb0 = __shfl_xor(b0, 32, 64);
        const unsigned int sb1 = __shfl_xor(b1, 32, 64);
        const unsigned int sa0 = __shfl_xor(a0, 32, 64);
        const unsigned int sa1 = __shfl_xor(a1, 32, 64);
        u32x4 wvec;
        wvec.x = lh ? sb0 : a0;
        wvec.y = lh ? sb1 : a1;
        wvec.z = lh ? b0 : sa0;
        wvec.w = lh ? b1 : sa1;
        pfrag[k2 * 2 + fb] = __builtin_bit_cast(bf16x8, wvec);
      }
    }

    __builtin_amdgcn_s_setprio(1);
#pragma unroll
    for (int dt = 0; dt < 4; ++dt) {
      const int d = dt * 32 + lq;
#pragma unroll
      for (int kk = 0; kk < 4; ++kk) {
        bf16x8 vf = *(const bf16x8*)(vb + d * 128 + ((((kk << 1) | lh) ^ (d & 7)) << 4));
        oacc[dt] = __builtin_amdgcn_mfma_f32_32x32x16_bf16(vf, pfrag[kk], oacc[dt], 0, 0, 0);
      }
    }
    __builtin_amdgcn_s_setprio(0);
    __syncthreads();
  }

  // epilogue: O^T -> LDS transpose -> coalesced store
  const float inv = 1.0f / lsum;
  bf16* ob = (bf16*)lds;
  const int qloc = wv * 32 + lq;
#pragma unroll
  for (int dt = 0; dt < 4; ++dt)
#pragma unroll
    for (int r = 0; r < 16; ++r) {
      const int d = dt * 32 + (r & 3) + 8 * (r >> 2) + 4 * lh;
      ob[qloc * 132 + d] = f2bf(oacc[dt][r] * inv);
    }
#pragma unroll
  for (int it = 0; it < 8; ++it) {
    const int c = it * 64 + ln;
    const int qq = c >> 4, dc = c & 15;
    const char* srcp = (const char*)ob + (wv * 32 + qq) * 264 + dc * 16;
    uint2 v0 = *(const uint2*)srcp;
    uint2 v1 = *(const uint2*)(srcp + 8);
    uint4 outv;
    outv.x = v0.x; outv.y = v0.y; outv.z = v1.x; outv.w = v1.y;
    *(uint4*)((char*)(ao + ((long)b * SEQ + qt * 256 + wv * 32 + qq) * DM + h * 128) + dc * 16) = outv;
  }
}

// ---------------- launch ----------------
extern "C" void kernel_launch(void* const* d_in, const int* in_sizes, int n_in,
                              void* d_out, int out_size, void* d_ws, size_t ws_size,
                              hipStream_t stream) {
  const float* x      = (const float*)d_in[0];
  const float* w_qkv  = (const float*)d_in[1];
  const float* w_proj = (const float*)d_in[2];
  const float* b_proj = (const float*)d_in[3];

  char* ws = (char*)d_ws;
  size_t off = 0;
  auto alloc = [&](size_t bytes) {
    void* p = ws + off;
    off += (bytes + 255) & ~(size_t)255;
    return p;
  };
  bf16* xb     = (bf16*)alloc((size_t)MROWS * DM * 2);
  bf16* wqkvb  = (bf16*)alloc((size_t)EQ * DM * 2);
  bf16* wprojb = (bf16*)alloc((size_t)DM * DM * 2);
  bf16* q_r    = (bf16*)alloc((size_t)Bz * H * SEQ * HD * 2);
  bf16* k_r    = (bf16*)alloc((size_t)Bz * H * SEQ * HD * 2);
  bf16* v_t    = (bf16*)alloc((size_t)Bz * H * SEQ * HD * 2);
  bf16* aob    = (bf16*)alloc((size_t)MROWS * DM * 2);
  float* ct    = (float*)alloc((size_t)SEQ * 64 * 4);
  float* st    = (float*)alloc((size_t)SEQ * 64 * 4);

  {
    long n = MROWS * DM;
    f32_to_bf16<<<(int)((n / 4 + 255) / 256), 256, 0, stream>>>(x, xb, n);
  }
  {
    long n = (long)EQ * DM;
    f32_to_bf16<<<(int)((n / 4 + 255) / 256), 256, 0, stream>>>(w_qkv, wqkvb, n);
  }
  {
    long n = (long)DM * DM;
    f32_to_bf16<<<(int)((n / 4 + 255) / 256), 256, 0, stream>>>(w_proj, wprojb, n);
  }
  rope_table<<<(SEQ * 64) / 256, 256, 0, stream>>>(ct, st);

  // GEMM1 + fused RoPE/reshape/V-transpose epilogue: grid 512 = 2 exact rounds
  gemm128<2048, 384, 3, 1><<<(int)(MROWS / 128) * (EQ / 384), 512, 0, stream>>>(
      xb, wqkvb, nullptr, nullptr, q_r, k_r, v_t, ct, st, (int)MROWS, EQ);

  // attn: 256 blocks (1 exact round), 8 waves each
  attn_fwd<<<256, 512, 0, stream>>>(q_r, k_r, v_t, aob);

  // GEMM2: 4096x2048x2048, BM=128 BN=256 -> grid 256 = 1 exact round
  gemm128<2048, 256, 2, 0><<<(int)(MROWS / 128) * (DM / 256), 512, 0, stream>>>(
      aob, wprojb, d_out, b_proj, nullptr, nullptr, nullptr, nullptr, nullptr,
      (int)MROWS, DM);
}